// Round 5
// baseline (9822.003 us; speedup 1.0000x reference)
//
#include <hip/hip_runtime.h>
#include <hip/hip_bf16.h>
#include <math.h>

#define NN 20000
#define NE 640000
#define H  128
#define RB 50
#define NL 6
#define EB 64

typedef unsigned short u16;

__device__ __forceinline__ float b2f(u16 u) {
  return __uint_as_float(((unsigned int)u) << 16);
}
// float-mode-dispatched loads: fm=0 f32, fm=1 bf16, fm=2 f64. i = element index.
__device__ __forceinline__ float ldw(const void* p, long i, int fm) {
  if (fm == 1) return b2f(((const u16*)p)[i]);
  if (fm == 2) return (float)((const double*)p)[i];
  return ((const float*)p)[i];
}
__device__ __forceinline__ float4 ldw4(const void* p, long i, int fm) {
  if (fm == 1) {
    ushort4 u = *(const ushort4*)((const u16*)p + i);
    return make_float4(b2f(u.x), b2f(u.y), b2f(u.z), b2f(u.w));
  }
  if (fm == 2) {
    const double* d = (const double*)p + i;
    return make_float4((float)d[0], (float)d[1], (float)d[2], (float)d[3]);
  }
  return *(const float4*)((const float*)p + i);
}
// int-width-dispatched load: im=1 -> int64 storage
__device__ __forceinline__ int ldi(const void* p, long i, int im) {
  return im ? (int)((const long long*)p)[i] : ((const int*)p)[i];
}

// flags[0] = float mode (0 f32 / 1 bf16 / 2 f64)
// flags[1] = int mode (0 i32 / 1 i64), probed from z
// flags[2] = means/betas swapped (0 normal)
// Probe values: rbf_means[0] = exp(-5) ~ 0.0067379; rbf_betas[k] ~ 633.5
__global__ void k_detect(const void* meansC, const void* betasC, const void* z,
                         int* flags) {
  // int mode from z (values in [0,100), random -> odd 32-bit words nonzero iff i32)
  const unsigned* u = (const unsigned*)z;
  unsigned se = 0, so = 0;
  for (int i = 0; i < 128; ++i) { se |= u[2 * i]; so |= u[2 * i + 1]; }
  flags[1] = (so == 0u && se != 0u) ? 1 : 0;
  // float mode: try f32, f64, bf16; accept if {m0,b0} looks like {means,betas}
  int fm = 0, swap = 0, found = 0;
  const int order[3] = {0, 2, 1};
  for (int t = 0; t < 3 && !found; ++t) {
    int m = order[t];
    float m0 = ldw(meansC, 0, m), b0 = ldw(betasC, 0, m);
    bool m_is_mean = (m0 > 0.004f && m0 < 1.01f);
    bool b_is_beta = (b0 > 300.f && b0 < 1200.f);
    bool m_is_beta = (m0 > 300.f && m0 < 1200.f);
    bool b_is_mean = (b0 > 0.004f && b0 < 1.01f);
    if (m_is_mean && b_is_beta) { fm = m; swap = 0; found = 1; }
    else if (m_is_beta && b_is_mean) { fm = m; swap = 1; found = 1; }
  }
  flags[0] = fm;
  flags[2] = swap;
}

__global__ void k_zero_f32(float* __restrict__ p, int n) {
  int i = blockIdx.x * blockDim.x + threadIdx.x;
  if (i < n) p[i] = 0.f;
}

__global__ void k_embed(const void* z, const void* emb, const void* nemb,
                        const int* __restrict__ flags,
                        float* __restrict__ x, float* __restrict__ xn) {
  int fm = flags[0], im = flags[1];
  int i = blockIdx.x * blockDim.x + threadIdx.x;
  if (i >= NN * H) return;
  int n = i >> 7, c = i & (H - 1);
  long o = (long)ldi(z, n, im) * H + c;
  x[i]  = ldw(emb,  o, fm);
  xn[i] = ldw(nemb, o, fm);
}

// OUTPUT IS FLOAT32 (out_npz = 9.5 MB ~ 2.56M f32 compressed; bf16 would be <=5.12 MB)
__global__ void k_out(const float* __restrict__ x, float* __restrict__ out) {
  int i = blockIdx.x * blockDim.x + threadIdx.x;
  if (i < NN * H) out[i] = x[i];
}

// ---------------- generic node GEMM ----------------
// out = act(A @ W[woff:] (+ bias[boff:])) (+ add)
__global__ __launch_bounds__(256) void k_gemm(
    const float* __restrict__ A, const void* W, long woff,
    const void* bias, long boff,
    const float* __restrict__ add, float* __restrict__ out, int useAct,
    const int* __restrict__ flags)
{
  __shared__ float sA[64][132];
  int fm = flags[0];
  int tid = threadIdx.x;
  int n0 = blockIdx.x * 64;
  #pragma unroll
  for (int j = 0; j < 8; ++j) {
    int f4 = tid + j * 256;
    int r = f4 >> 5, c4 = f4 & 31;
    int n = n0 + r;
    float4 v = make_float4(0.f, 0.f, 0.f, 0.f);
    if (n < NN) v = *(const float4*)&A[(size_t)n * H + c4 * 4];
    *(float4*)&sA[r][c4 * 4] = v;
  }
  __syncthreads();
  int g = tid >> 5;
  int c0 = (tid & 31) * 4;
  int eb = g * 8;
  float acc[8][4];
  #pragma unroll
  for (int i = 0; i < 8; ++i)
    for (int j = 0; j < 4; ++j) acc[i][j] = 0.f;
  for (int k = 0; k < H; ++k) {
    float4 wv = ldw4(W, woff + (long)k * H + c0, fm);
    #pragma unroll
    for (int i = 0; i < 8; ++i) {
      float a = sA[eb + i][k];
      acc[i][0] += a * wv.x; acc[i][1] += a * wv.y;
      acc[i][2] += a * wv.z; acc[i][3] += a * wv.w;
    }
  }
  float bv[4] = {0.f, 0.f, 0.f, 0.f};
  if (bias) {
    float4 b4 = ldw4(bias, boff + c0, fm);
    bv[0] = b4.x; bv[1] = b4.y; bv[2] = b4.z; bv[3] = b4.w;
  }
  #pragma unroll
  for (int i = 0; i < 8; ++i) {
    int n = n0 + eb + i;
    if (n >= NN) break;
    float o[4];
    #pragma unroll
    for (int j = 0; j < 4; ++j) {
      float v = acc[i][j] + bv[j];
      if (useAct) v = v / (1.f + __expf(-v));
      o[j] = v;
    }
    if (add) {
      float4 a4 = *(const float4*)&add[(size_t)n * H + c0];
      o[0] += a4.x; o[1] += a4.y; o[2] += a4.z; o[3] += a4.w;
    }
    *(float4*)&out[(size_t)n * H + c0] = make_float4(o[0], o[1], o[2], o[3]);
  }
}

// ---------------- neighbor embedding: per-edge, atomic scatter ----------------
__global__ __launch_bounds__(256) void k_nbrE(
    const void* ei, const void* pos, const void* meansC,
    const void* betasC, const void* W, const void* b,
    const float* __restrict__ xn, float* __restrict__ agg,
    const int* __restrict__ flags)
{
  __shared__ float s_attr[EB][52];
  __shared__ int s_src[EB], s_dst[EB];
  __shared__ float s_C[EB], s_tv[EB];
  int fm = flags[0], im = flags[1];
  const void* means = flags[2] ? betasC : meansC;
  const void* betas = flags[2] ? meansC : betasC;
  int tid = threadIdx.x;
  int base = blockIdx.x * EB;
  if (tid < EB) {
    int ge = base + tid;
    int s = ldi(ei, ge, im), t = ldi(ei, (long)NE + ge, im);
    s_src[tid] = s; s_dst[tid] = t;
    float dx = ldw(pos, 3l*s,   fm) - ldw(pos, 3l*t,   fm);
    float dy = ldw(pos, 3l*s+1, fm) - ldw(pos, 3l*t+1, fm);
    float dz = ldw(pos, 3l*s+2, fm) - ldw(pos, 3l*t+2, fm);
    float d = sqrtf(dx*dx + dy*dy + dz*dz);
    float C = 0.5f * (cosf(d * 0.628318530717958647692f) + 1.0f);
    if (d >= 5.0f) C = 0.f;
    s_C[tid] = C;
    s_tv[tid] = expf(-d);
  }
  __syncthreads();
  {
    int e = tid & 63, kb = tid >> 6;
    float tv = s_tv[e], Ce = s_C[e];
    for (int k = kb; k < RB; k += 4) {
      float diff = tv - ldw(means, k, fm);
      s_attr[e][k] = Ce * __expf(-ldw(betas, k, fm) * diff * diff);
    }
  }
  __syncthreads();
  int g = tid >> 5, c0 = (tid & 31) * 4;
  int eb = g * 8;
  float acc[8][4];
  #pragma unroll
  for (int i = 0; i < 8; ++i)
    for (int j = 0; j < 4; ++j) acc[i][j] = 0.f;
  for (int k = 0; k < RB; ++k) {
    float4 wv = ldw4(W, (long)k * H + c0, fm);
    #pragma unroll
    for (int i = 0; i < 8; ++i) {
      float a = s_attr[eb + i][k];
      acc[i][0] += a * wv.x; acc[i][1] += a * wv.y;
      acc[i][2] += a * wv.z; acc[i][3] += a * wv.w;
    }
  }
  float4 bv = ldw4(b, (long)c0, fm);
  #pragma unroll
  for (int i = 0; i < 8; ++i) {
    int e = eb + i;
    float m = (s_src[e] != s_dst[e]) ? s_C[e] : 0.f;
    const float* hp = &xn[(size_t)s_src[e] * H + c0];
    float* ap = &agg[(size_t)s_dst[e] * H + c0];
    atomicAdd(ap + 0, (acc[i][0] + bv.x) * m * hp[0]);
    atomicAdd(ap + 1, (acc[i][1] + bv.y) * m * hp[1]);
    atomicAdd(ap + 2, (acc[i][2] + bv.z) * m * hp[2]);
    atomicAdd(ap + 3, (acc[i][3] + bv.w) * m * hp[3]);
  }
}

// ---------------- CFConv: filter MLP + gather + atomic scatter ----------------
__global__ __launch_bounds__(256) void k_cfE(
    const void* ei, const void* pos, const void* meansC,
    const void* betasC, const void* W1, long w1off, const void* b1, long b1off,
    const void* W2, long w2off, const void* b2, long b2off,
    const float* __restrict__ h, float* __restrict__ agg,
    const int* __restrict__ flags)
{
  __shared__ float s_attr[EB][52];
  __shared__ float s_t1[EB * 132];
  __shared__ int s_src[EB], s_dst[EB];
  __shared__ float s_C[EB], s_tv[EB];
  int fm = flags[0], im = flags[1];
  const void* means = flags[2] ? betasC : meansC;
  const void* betas = flags[2] ? meansC : betasC;
  int tid = threadIdx.x;
  int base = blockIdx.x * EB;
  if (tid < EB) {
    int ge = base + tid;
    int s = ldi(ei, ge, im), t = ldi(ei, (long)NE + ge, im);
    s_src[tid] = s; s_dst[tid] = t;
    float dx = ldw(pos, 3l*s,   fm) - ldw(pos, 3l*t,   fm);
    float dy = ldw(pos, 3l*s+1, fm) - ldw(pos, 3l*t+1, fm);
    float dz = ldw(pos, 3l*s+2, fm) - ldw(pos, 3l*t+2, fm);
    float d = sqrtf(dx*dx + dy*dy + dz*dz);
    float C = 0.5f * (cosf(d * 0.628318530717958647692f) + 1.0f);
    if (d >= 5.0f) C = 0.f;
    s_C[tid] = C;
    s_tv[tid] = expf(-d);
  }
  __syncthreads();
  {
    int e = tid & 63, kb = tid >> 6;
    float tv = s_tv[e], Ce = s_C[e];
    for (int k = kb; k < RB; k += 4) {
      float diff = tv - ldw(means, k, fm);
      s_attr[e][k] = Ce * __expf(-ldw(betas, k, fm) * diff * diff);
    }
  }
  __syncthreads();
  int g = tid >> 5, c0 = (tid & 31) * 4;
  int eb = g * 8;
  // GEMM1: attr[64,50] @ W1[50,128], +b1, silu -> s_t1
  float acc[8][4];
  #pragma unroll
  for (int i = 0; i < 8; ++i)
    for (int j = 0; j < 4; ++j) acc[i][j] = 0.f;
  for (int k = 0; k < RB; ++k) {
    float4 wv = ldw4(W1, w1off + (long)k * H + c0, fm);
    #pragma unroll
    for (int i = 0; i < 8; ++i) {
      float a = s_attr[eb + i][k];
      acc[i][0] += a * wv.x; acc[i][1] += a * wv.y;
      acc[i][2] += a * wv.z; acc[i][3] += a * wv.w;
    }
  }
  float4 b1v = ldw4(b1, b1off + c0, fm);
  #pragma unroll
  for (int i = 0; i < 8; ++i) {
    float v0 = acc[i][0] + b1v.x, v1 = acc[i][1] + b1v.y;
    float v2 = acc[i][2] + b1v.z, v3 = acc[i][3] + b1v.w;
    v0 = v0 / (1.f + __expf(-v0)); v1 = v1 / (1.f + __expf(-v1));
    v2 = v2 / (1.f + __expf(-v2)); v3 = v3 / (1.f + __expf(-v3));
    *(float4*)&s_t1[(eb + i) * 132 + c0] = make_float4(v0, v1, v2, v3);
  }
  __syncthreads();
  // GEMM2: t1[64,128] @ W2[128,128]
  float acc2[8][4];
  #pragma unroll
  for (int i = 0; i < 8; ++i)
    for (int j = 0; j < 4; ++j) acc2[i][j] = 0.f;
  for (int k = 0; k < H; ++k) {
    float4 wv = ldw4(W2, w2off + (long)k * H + c0, fm);
    #pragma unroll
    for (int i = 0; i < 8; ++i) {
      float a = s_t1[(eb + i) * 132 + k];
      acc2[i][0] += a * wv.x; acc2[i][1] += a * wv.y;
      acc2[i][2] += a * wv.z; acc2[i][3] += a * wv.w;
    }
  }
  float4 b2v = ldw4(b2, b2off + c0, fm);
  #pragma unroll
  for (int i = 0; i < 8; ++i) {
    int e = eb + i;
    float Ce = s_C[e];
    const float* hp = &h[(size_t)s_src[e] * H + c0];
    float* ap = &agg[(size_t)s_dst[e] * H + c0];
    atomicAdd(ap + 0, (acc2[i][0] + b2v.x) * Ce * hp[0]);
    atomicAdd(ap + 1, (acc2[i][1] + b2v.y) * Ce * hp[1]);
    atomicAdd(ap + 2, (acc2[i][2] + b2v.z) * Ce * hp[2]);
    atomicAdd(ap + 3, (acc2[i][3] + b2v.w) * Ce * hp[3]);
  }
}

// ---------------- launcher ----------------
extern "C" void kernel_launch(void* const* d_in, const int* in_sizes, int n_in,
                              void* d_out, int out_size, void* d_ws, size_t ws_size,
                              hipStream_t stream) {
  // dict order: z,pos,edge_index,batch,emb,nemb,npW,npb,cW,cb,means,betas,
  //             W1,b1,W2,b2,l1W,l2W,l2b,lW,lb
  // If the harness drops the unused `batch`, everything after index 2 shifts by 1.
  int bo = (n_in >= 4 && in_sizes[3] == NN) ? 0 : -1;  // batch present? (else emb@3)
  const void* z     = d_in[0];
  const void* pos   = d_in[1];
  const void* ei    = d_in[2];
  const void* emb   = d_in[4 + bo];
  const void* nemb  = d_in[5 + bo];
  const void* npW   = d_in[6 + bo];
  const void* npb   = d_in[7 + bo];
  const void* cW    = d_in[8 + bo];
  const void* cb    = d_in[9 + bo];
  const void* means = d_in[10 + bo];
  const void* betas = d_in[11 + bo];
  const void* W1    = d_in[12 + bo];
  const void* b1    = d_in[13 + bo];
  const void* W2    = d_in[14 + bo];
  const void* b2    = d_in[15 + bo];
  const void* l1W   = d_in[16 + bo];
  const void* l2W   = d_in[17 + bo];
  const void* l2b   = d_in[18 + bo];
  const void* lW    = d_in[19 + bo];
  const void* lb    = d_in[20 + bo];

  int*   flags = (int*)d_ws;
  float* xbuf  = (float*)((char*)d_ws + 64);
  float* bufA  = xbuf + (size_t)NN * H;
  float* agg   = bufA + (size_t)NN * H;

  dim3 b256(256);
  int gNH = (NN * H + 255) / 256;      // 10000
  int gE  = NE / EB;                   // 10000
  int gG  = (NN + 63) / 64;            // 313

  k_detect<<<1, 1, 0, stream>>>(means, betas, z, flags);
  k_embed<<<gNH, b256, 0, stream>>>(z, emb, nemb, flags, xbuf, bufA);
  k_zero_f32<<<gNH, b256, 0, stream>>>(agg, NN * H);
  k_nbrE<<<gE, b256, 0, stream>>>(ei, pos, means, betas, npW, npb, bufA, agg, flags);

  // combine: x = [x || agg] @ cW + cb
  k_gemm<<<gG, b256, 0, stream>>>(xbuf, cW, 0l, cb, 0l, nullptr, bufA, 0, flags);
  k_gemm<<<gG, b256, 0, stream>>>(agg, cW, (long)128 * H, nullptr, 0l, bufA, xbuf, 0, flags);

  for (int l = 0; l < NL; ++l) {
    long oWH = (long)l * H * H, oRH = (long)l * RB * H, oB = (long)l * H;
    k_gemm<<<gG, b256, 0, stream>>>(xbuf, l1W, oWH, nullptr, 0l, nullptr, bufA, 0, flags);
    k_zero_f32<<<gNH, b256, 0, stream>>>(agg, NN * H);
    k_cfE<<<gE, b256, 0, stream>>>(ei, pos, means, betas,
                                   W1, oRH, b1, oB, W2, oWH, b2, oB,
                                   bufA, agg, flags);
    k_gemm<<<gG, b256, 0, stream>>>(agg, l2W, oWH, l2b, oB, nullptr, bufA, 1, flags);
    k_gemm<<<gG, b256, 0, stream>>>(bufA, lW, oWH, lb, oB, xbuf, xbuf, 0, flags);
  }
  k_out<<<gNH, b256, 0, stream>>>(xbuf, (float*)d_out);
}

// Round 7
// 1983.618 us; speedup vs baseline: 4.9516x; 4.9516x over previous
//
#include <hip/hip_runtime.h>
#include <hip/hip_bf16.h>
#include <math.h>

#define NN 20000
#define NE 640000
#define H  128
#define RB 50
#define NL 6

typedef unsigned short u16;
typedef __attribute__((ext_vector_type(8))) short short8v;
typedef __attribute__((ext_vector_type(4))) float f32x4;

__device__ __forceinline__ u16 f2b(float v) {
  unsigned x = __float_as_uint(v);
  unsigned r = (x + 0x7FFFu + ((x >> 16) & 1u)) >> 16;
  return (u16)r;
}

// ---------------- sort machinery ----------------
__global__ void k_zero_i32(int* __restrict__ p, int n) {
  int i = blockIdx.x * blockDim.x + threadIdx.x;
  if (i < n) p[i] = 0;
}
__global__ void k_zero_f32(float* __restrict__ p, int n) {
  int i = blockIdx.x * blockDim.x + threadIdx.x;
  if (i < n) p[i] = 0.f;
}
__global__ void k_hist(const int* __restrict__ ei, int* __restrict__ counts) {
  int e = blockIdx.x * blockDim.x + threadIdx.x;
  if (e < NE) atomicAdd(&counts[ei[NE + e]], 1);
}
__global__ void k_scan(const int* __restrict__ counts, int* __restrict__ cursor) {
  __shared__ int buf[1024];
  __shared__ int carry;
  int tid = threadIdx.x;
  if (tid == 0) carry = 0;
  __syncthreads();
  for (int base = 0; base < NN; base += 1024) {
    int i = base + tid;
    int v = (i < NN) ? counts[i] : 0;
    buf[tid] = v;
    __syncthreads();
    for (int off = 1; off < 1024; off <<= 1) {
      int t = (tid >= off) ? buf[tid - off] : 0;
      __syncthreads();
      buf[tid] += t;
      __syncthreads();
    }
    int incl = buf[tid];
    int excl = incl - v + carry;
    if (i < NN) cursor[i] = excl;
    __syncthreads();
    if (tid == 1023) carry += incl;
    __syncthreads();
  }
}
__global__ void k_place(const int* __restrict__ ei, int* __restrict__ cursor,
                        int* __restrict__ perm) {
  int e = blockIdx.x * blockDim.x + threadIdx.x;
  if (e < NE) {
    int d = ei[NE + e];
    int p = atomicAdd(&cursor[d], 1);
    perm[p] = e;
  }
}

// ---------------- edge precompute: sorted meta + bf16 RBF features [E][64] ----------------
__global__ void k_edge(const int* __restrict__ ei, const int* __restrict__ perm,
                       const float* __restrict__ pos, const float* __restrict__ means,
                       const float* __restrict__ betas,
                       int* __restrict__ srcS, int* __restrict__ dstS,
                       float* __restrict__ CS, u16* __restrict__ attrG) {
  int p = blockIdx.x * 256 + threadIdx.x;
  if (p >= NE) return;
  int e = perm[p];
  int s = ei[e], t = ei[NE + e];
  srcS[p] = s; dstS[p] = t;
  float dx = pos[3*s]   - pos[3*t];
  float dy = pos[3*s+1] - pos[3*t+1];
  float dz = pos[3*s+2] - pos[3*t+2];
  float d = sqrtf(dx*dx + dy*dy + dz*dz);
  float C = 0.5f * (cosf(d * 0.628318530717958647692f) + 1.0f);
  if (d >= 5.0f) C = 0.f;
  CS[p] = C;
  float tv = expf(-d);
  u16* row = attrG + (size_t)p * 64;
  for (int k = 0; k < RB; ++k) {
    float diff = tv - means[k];
    row[k] = f2b(C * expf(-betas[k] * diff * diff));
  }
  for (int k = RB; k < 64; ++k) row[k] = 0;
}

// ---------------- weight pre-transpose/convert to bf16 ----------------
// npWt[n][k] [128][64]; w1tA[l][n][k] [6][128][64]; w2tA[l][n][k] [6][128][136]
__global__ void k_prepw(const float* __restrict__ npW, const float* __restrict__ W1,
                        const float* __restrict__ W2, u16* __restrict__ npWt,
                        u16* __restrict__ w1tA, u16* __restrict__ w2tA) {
  int i = blockIdx.x * 256 + threadIdx.x;
  if (i < 8192) {
    int n = i >> 6, k = i & 63;
    npWt[i] = (k < RB) ? f2b(npW[k * H + n]) : (u16)0;
  } else if (i < 57344) {
    int j = i - 8192;
    int l = j >> 13, r = j & 8191;
    int n = r >> 6, k = r & 63;
    w1tA[j] = (k < RB) ? f2b(W1[(size_t)l * RB * H + (size_t)k * H + n]) : (u16)0;
  } else if (i < 161792) {
    int j = i - 57344;
    int l = j / 17408, r = j % 17408;
    int n = r / 136, k = r % 136;
    w2tA[j] = (k < H) ? f2b(W2[(size_t)l * H * H + (size_t)k * H + n]) : (u16)0;
  }
}

__global__ void k_embed(const int* __restrict__ z, const float* __restrict__ emb,
                        const float* __restrict__ nemb,
                        float* __restrict__ x, float* __restrict__ xn) {
  int i = blockIdx.x * blockDim.x + threadIdx.x;
  if (i >= NN * H) return;
  int n = i >> 7, c = i & (H - 1);
  long o = (long)z[n] * H + c;
  x[i]  = emb[o];
  xn[i] = nemb[o];
}

__global__ void k_out(const float* __restrict__ x, float* __restrict__ out) {
  int i = blockIdx.x * blockDim.x + threadIdx.x;
  if (i < NN * H) out[i] = x[i];
}

// ---------------- node GEMM, M-tile 32 ----------------
__global__ __launch_bounds__(256) void k_gemm32(
    const float* __restrict__ A, const float* __restrict__ W,
    const float* __restrict__ bias, const float* __restrict__ add,
    float* __restrict__ out, int useAct)
{
  __shared__ float sA[32][132];
  int tid = threadIdx.x;
  int n0 = blockIdx.x * 32;
  #pragma unroll
  for (int j = 0; j < 4; ++j) {
    int f4 = tid + j * 256;
    int r = f4 >> 5, c4 = f4 & 31;
    *(float4*)&sA[r][c4 * 4] = *(const float4*)&A[(size_t)(n0 + r) * H + c4 * 4];
  }
  __syncthreads();
  int g = tid >> 5;
  int c0 = (tid & 31) * 4;
  int eb = g * 4;
  float acc[4][4];
  #pragma unroll
  for (int i = 0; i < 4; ++i)
    for (int j = 0; j < 4; ++j) acc[i][j] = 0.f;
  for (int k = 0; k < H; ++k) {
    float4 wv = *(const float4*)&W[(size_t)k * H + c0];
    #pragma unroll
    for (int i = 0; i < 4; ++i) {
      float a = sA[eb + i][k];
      acc[i][0] += a * wv.x; acc[i][1] += a * wv.y;
      acc[i][2] += a * wv.z; acc[i][3] += a * wv.w;
    }
  }
  float bv[4] = {0.f, 0.f, 0.f, 0.f};
  if (bias) {
    float4 b4 = *(const float4*)&bias[c0];
    bv[0] = b4.x; bv[1] = b4.y; bv[2] = b4.z; bv[3] = b4.w;
  }
  #pragma unroll
  for (int i = 0; i < 4; ++i) {
    int n = n0 + eb + i;
    float o[4];
    #pragma unroll
    for (int j = 0; j < 4; ++j) {
      float v = acc[i][j] + bv[j];
      if (useAct) v = v / (1.f + __expf(-v));
      o[j] = v;
    }
    if (add) {
      float4 a4 = *(const float4*)&add[(size_t)n * H + c0];
      o[0] += a4.x; o[1] += a4.y; o[2] += a4.z; o[3] += a4.w;
    }
    *(float4*)&out[(size_t)n * H + c0] = make_float4(o[0], o[1], o[2], o[3]);
  }
}

// ---------------- MFMA neighbor embedding (GEMM1 only) ----------------
// A-fragments (attr) and B-fragments (weights) loaded DIRECTLY from global:
// attr has zero intra-block reuse; weights are L1/L2-resident (shared by all blocks).
__global__ __launch_bounds__(256) void k_nbr_mfma(
    const int* __restrict__ srcS, const int* __restrict__ dstS,
    const float* __restrict__ CS, const u16* __restrict__ attrG,
    const u16* __restrict__ npWt, const float* __restrict__ npb,
    const float* __restrict__ xn, float* __restrict__ agg)
{
  __shared__ int s_src[128], s_dst[128];
  __shared__ float s_C[128];
  int tid = threadIdx.x;
  int lane = tid & 63, wv = tid >> 6;
  long base = (long)blockIdx.x * 128;
  if (tid < 128) {
    s_src[tid] = srcS[base + tid];
    s_dst[tid] = dstS[base + tid];
    s_C[tid]   = CS[base + tid];
  }
  __syncthreads();
  int r16 = lane & 15, g4 = lane >> 4;
  f32x4 acc[2][8];
  #pragma unroll
  for (int rl = 0; rl < 2; ++rl)
    for (int ct = 0; ct < 8; ++ct) acc[rl][ct] = (f32x4){0.f,0.f,0.f,0.f};
  #pragma unroll
  for (int kt = 0; kt < 2; ++kt) {
    short8v aF[2];
    #pragma unroll
    for (int rl = 0; rl < 2; ++rl)
      aF[rl] = *(const short8v*)&attrG[(base + (wv*2+rl)*16 + r16) * 64 + kt*32 + g4*8];
    #pragma unroll
    for (int ct = 0; ct < 8; ++ct) {
      short8v bF = *(const short8v*)&npWt[(ct*16 + r16) * 64 + kt*32 + g4*8];
      #pragma unroll
      for (int rl = 0; rl < 2; ++rl)
        acc[rl][ct] = __builtin_amdgcn_mfma_f32_16x16x32_bf16(aF[rl], bF, acc[rl][ct], 0, 0, 0);
    }
  }
  float bb[8];
  #pragma unroll
  for (int ct = 0; ct < 8; ++ct) bb[ct] = npb[ct*16 + r16];
  float vsum[8];
  int pdst = -1;
  #pragma unroll
  for (int rl = 0; rl < 2; ++rl) {
    #pragma unroll
    for (int r = 0; r < 4; ++r) {
      int e = (wv*2+rl)*16 + g4*4 + r;
      int dn = s_dst[e];
      float m = (s_src[e] != dn) ? s_C[e] : 0.f;
      const float* hp = xn + (size_t)s_src[e] * H + r16;
      if (dn != pdst) {
        if (pdst >= 0) {
          float* ap = agg + (size_t)pdst * H + r16;
          #pragma unroll
          for (int ct = 0; ct < 8; ++ct) atomicAdd(ap + ct*16, vsum[ct]);
        }
        #pragma unroll
        for (int ct = 0; ct < 8; ++ct) vsum[ct] = 0.f;
        pdst = dn;
      }
      #pragma unroll
      for (int ct = 0; ct < 8; ++ct)
        vsum[ct] += (acc[rl][ct][r] + bb[ct]) * m * hp[ct*16];
    }
  }
  {
    float* ap = agg + (size_t)pdst * H + r16;
    #pragma unroll
    for (int ct = 0; ct < 8; ++ct) atomicAdd(ap + ct*16, vsum[ct]);
  }
}

// ---------------- MFMA CFConv: MLP + gather + run-merge scatter ----------------
// LDS: only t1 (the GEMM1->GEMM2 transpose) + edge meta = 36.4 KB (< 64 KB limit).
// t1 rows are written and read by the SAME wave's 32-row band -> no barrier needed.
__global__ __launch_bounds__(256) void k_cf_mfma(
    const int* __restrict__ srcS, const int* __restrict__ dstS,
    const float* __restrict__ CS, const u16* __restrict__ attrG,
    const u16* __restrict__ w1t, const float* __restrict__ b1,
    const u16* __restrict__ w2t, const float* __restrict__ b2,
    const float* __restrict__ h, float* __restrict__ agg)
{
  __shared__ __align__(16) u16 s_t1[128 * 136];   // 34816 B
  __shared__ int s_src[128], s_dst[128];
  __shared__ float s_C[128];
  int tid = threadIdx.x;
  int lane = tid & 63, wv = tid >> 6;
  long base = (long)blockIdx.x * 128;
  if (tid < 128) {
    s_src[tid] = srcS[base + tid];
    s_dst[tid] = dstS[base + tid];
    s_C[tid]   = CS[base + tid];
  }
  __syncthreads();
  int r16 = lane & 15, g4 = lane >> 4;
  // GEMM1: attr[128x64] @ W1t -> acc1 (A,B fragments straight from global)
  f32x4 acc1[2][8];
  #pragma unroll
  for (int rl = 0; rl < 2; ++rl)
    for (int ct = 0; ct < 8; ++ct) acc1[rl][ct] = (f32x4){0.f,0.f,0.f,0.f};
  #pragma unroll
  for (int kt = 0; kt < 2; ++kt) {
    short8v aF[2];
    #pragma unroll
    for (int rl = 0; rl < 2; ++rl)
      aF[rl] = *(const short8v*)&attrG[(base + (wv*2+rl)*16 + r16) * 64 + kt*32 + g4*8];
    #pragma unroll
    for (int ct = 0; ct < 8; ++ct) {
      short8v bF = *(const short8v*)&w1t[(ct*16 + r16) * 64 + kt*32 + g4*8];
      #pragma unroll
      for (int rl = 0; rl < 2; ++rl)
        acc1[rl][ct] = __builtin_amdgcn_mfma_f32_16x16x32_bf16(aF[rl], bF, acc1[rl][ct], 0, 0, 0);
    }
  }
  // bias + silu -> bf16 t1 (wave-local rows)
  #pragma unroll
  for (int ct = 0; ct < 8; ++ct) {
    int c = ct*16 + r16;
    float bb = b1[c];
    #pragma unroll
    for (int rl = 0; rl < 2; ++rl) {
      int rbase = (wv*2+rl)*16 + g4*4;
      #pragma unroll
      for (int r = 0; r < 4; ++r) {
        float v = acc1[rl][ct][r] + bb;
        v = v / (1.f + __expf(-v));
        s_t1[(rbase + r) * 136 + c] = f2b(v);
      }
    }
  }
  // GEMM2: t1[128x128] @ W2t (A from LDS own band, B from global)
  f32x4 acc2[2][8];
  #pragma unroll
  for (int rl = 0; rl < 2; ++rl)
    for (int ct = 0; ct < 8; ++ct) acc2[rl][ct] = (f32x4){0.f,0.f,0.f,0.f};
  #pragma unroll
  for (int kt = 0; kt < 4; ++kt) {
    short8v aF[2];
    #pragma unroll
    for (int rl = 0; rl < 2; ++rl)
      aF[rl] = *(const short8v*)&s_t1[((wv*2+rl)*16 + r16) * 136 + kt*32 + g4*8];
    #pragma unroll
    for (int ct = 0; ct < 8; ++ct) {
      short8v bF = *(const short8v*)&w2t[(ct*16 + r16) * 136 + kt*32 + g4*8];
      #pragma unroll
      for (int rl = 0; rl < 2; ++rl)
        acc2[rl][ct] = __builtin_amdgcn_mfma_f32_16x16x32_bf16(aF[rl], bF, acc2[rl][ct], 0, 0, 0);
    }
  }
  // epilogue: Wf = (acc2 + b2) * C; val = Wf * h[src][c]; run-merge atomics (dst sorted)
  float bb2[8];
  #pragma unroll
  for (int ct = 0; ct < 8; ++ct) bb2[ct] = b2[ct*16 + r16];
  float vsum[8];
  int pdst = -1;
  #pragma unroll
  for (int rl = 0; rl < 2; ++rl) {
    #pragma unroll
    for (int r = 0; r < 4; ++r) {
      int e = (wv*2+rl)*16 + g4*4 + r;
      int dn = s_dst[e];
      float Ce = s_C[e];
      const float* hp = h + (size_t)s_src[e] * H + r16;
      if (dn != pdst) {
        if (pdst >= 0) {
          float* ap = agg + (size_t)pdst * H + r16;
          #pragma unroll
          for (int ct = 0; ct < 8; ++ct) atomicAdd(ap + ct*16, vsum[ct]);
        }
        #pragma unroll
        for (int ct = 0; ct < 8; ++ct) vsum[ct] = 0.f;
        pdst = dn;
      }
      #pragma unroll
      for (int ct = 0; ct < 8; ++ct)
        vsum[ct] += (acc2[rl][ct][r] + bb2[ct]) * Ce * hp[ct*16];
    }
  }
  {
    float* ap = agg + (size_t)pdst * H + r16;
    #pragma unroll
    for (int ct = 0; ct < 8; ++ct) atomicAdd(ap + ct*16, vsum[ct]);
  }
}

// ---------------- launcher ----------------
extern "C" void kernel_launch(void* const* d_in, const int* in_sizes, int n_in,
                              void* d_out, int out_size, void* d_ws, size_t ws_size,
                              hipStream_t stream) {
  int bo = (n_in >= 4 && in_sizes[3] == NN) ? 0 : -1;  // batch present?
  const int*   z     = (const int*)d_in[0];
  const float* pos   = (const float*)d_in[1];
  const int*   ei    = (const int*)d_in[2];
  const float* emb   = (const float*)d_in[4 + bo];
  const float* nemb  = (const float*)d_in[5 + bo];
  const float* npW   = (const float*)d_in[6 + bo];
  const float* npb   = (const float*)d_in[7 + bo];
  const float* cW    = (const float*)d_in[8 + bo];
  const float* cb    = (const float*)d_in[9 + bo];
  const float* means = (const float*)d_in[10 + bo];
  const float* betas = (const float*)d_in[11 + bo];
  const float* W1    = (const float*)d_in[12 + bo];
  const float* b1    = (const float*)d_in[13 + bo];
  const float* W2    = (const float*)d_in[14 + bo];
  const float* b2    = (const float*)d_in[15 + bo];
  const float* l1W   = (const float*)d_in[16 + bo];
  const float* l2W   = (const float*)d_in[17 + bo];
  const float* l2b   = (const float*)d_in[18 + bo];
  const float* lW    = (const float*)d_in[19 + bo];
  const float* lb    = (const float*)d_in[20 + bo];

  char* w = (char*)d_ws;
  auto alloc = [&](size_t bytes) { char* p = w; w += (bytes + 255) & ~(size_t)255; return p; };
  int*   counts = (int*)  alloc((size_t)NN * 4);
  int*   cursor = (int*)  alloc((size_t)NN * 4);
  int*   perm   = (int*)  alloc((size_t)NE * 4);
  int*   srcS   = (int*)  alloc((size_t)NE * 4);
  int*   dstS   = (int*)  alloc((size_t)NE * 4);
  float* CS     = (float*)alloc((size_t)NE * 4);
  u16*   attrG  = (u16*)  alloc((size_t)NE * 64 * 2);
  u16*   npWt   = (u16*)  alloc((size_t)128 * 64 * 2);
  u16*   w1tA   = (u16*)  alloc((size_t)NL * 128 * 64 * 2);
  u16*   w2tA   = (u16*)  alloc((size_t)NL * 128 * 136 * 2);
  float* xbuf   = (float*)alloc((size_t)NN * H * 4);
  float* bufA   = (float*)alloc((size_t)NN * H * 4);
  float* agg    = (float*)alloc((size_t)NN * H * 4);

  dim3 b256(256);
  int gE256 = (NE + 255) / 256;        // 2500
  int gNH   = (NN * H + 255) / 256;    // 10000
  int gCF   = NE / 128;                // 5000
  int gG    = NN / 32;                 // 625

  // sort by dst + edge precompute
  k_zero_i32<<<(NN + 255) / 256, b256, 0, stream>>>(counts, NN);
  k_hist<<<gE256, b256, 0, stream>>>(ei, counts);
  k_scan<<<1, 1024, 0, stream>>>(counts, cursor);
  k_place<<<gE256, b256, 0, stream>>>(ei, cursor, perm);
  k_edge<<<gE256, b256, 0, stream>>>(ei, perm, pos, means, betas, srcS, dstS, CS, attrG);
  k_prepw<<<(161792 + 255) / 256, b256, 0, stream>>>(npW, W1, W2, npWt, w1tA, w2tA);
  k_embed<<<gNH, b256, 0, stream>>>(z, emb, nemb, xbuf, bufA);

  // neighbor embedding
  k_zero_f32<<<gNH, b256, 0, stream>>>(agg, NN * H);
  k_nbr_mfma<<<gCF, b256, 0, stream>>>(srcS, dstS, CS, attrG, npWt, npb, bufA, agg);

  // combine: x = [x || agg] @ cW + cb
  k_gemm32<<<gG, b256, 0, stream>>>(xbuf, cW, cb, nullptr, bufA, 0);
  k_gemm32<<<gG, b256, 0, stream>>>(agg, cW + (size_t)128 * H, nullptr, bufA, xbuf, 0);

  for (int l = 0; l < NL; ++l) {
    k_gemm32<<<gG, b256, 0, stream>>>(xbuf, l1W + (size_t)l * H * H, nullptr, nullptr, bufA, 0);
    k_zero_f32<<<gNH, b256, 0, stream>>>(agg, NN * H);
    k_cf_mfma<<<gCF, b256, 0, stream>>>(srcS, dstS, CS, attrG,
                                        w1tA + (size_t)l * 128 * 64, b1 + (size_t)l * H,
                                        w2tA + (size_t)l * 128 * 136, b2 + (size_t)l * H,
                                        bufA, agg);
    k_gemm32<<<gG, b256, 0, stream>>>(agg, l2W + (size_t)l * H * H, l2b + (size_t)l * H,
                                      nullptr, bufA, 1);
    k_gemm32<<<gG, b256, 0, stream>>>(bufA, lW + (size_t)l * H * H, lb + (size_t)l * H,
                                      xbuf, xbuf, 0);
  }
  k_out<<<gNH, b256, 0, stream>>>(xbuf, (float*)d_out);
}